// Round 4
// baseline (65.067 us; speedup 1.0000x reference)
//
#include <hip/hip_runtime.h>
#include <hip/hip_bf16.h>

typedef __attribute__((ext_vector_type(8))) _Float16 half8;
typedef __attribute__((ext_vector_type(4))) _Float16 half4;
typedef __attribute__((ext_vector_type(4))) float f32x4;

#define MFMAH(a,b,c) __builtin_amdgcn_mfma_f32_16x16x32_f16(a,b,c,0,0,0)

#define LOG2_10K_64 0.2076205059304595f
#define INV2PI 0.15915494309189535f

// ---------------------------------------------------------------------------
// Prep: W1 (2048x128 f32) -> W1t[n][k] f16 (coalesced LDS-tile transpose);
// Wq/Wk/Wv (128x128) -> transposed f16 concatenated.
// ---------------------------------------------------------------------------
__global__ __launch_bounds__(256) void k_prep(const float* __restrict__ W1,
                                              const float* __restrict__ Wq,
                                              const float* __restrict__ Wk,
                                              const float* __restrict__ Wv,
                                              _Float16* __restrict__ W1t,
                                              _Float16* __restrict__ Wqkvt) {
  const int bid = blockIdx.x, tid = threadIdx.x;
  if (bid < 64) {
    __shared__ float Tl[64][65];
    const int kt0 = (bid >> 1) * 64, nt0 = (bid & 1) * 64;
    const int row = tid >> 2, c0 = (tid & 3) * 16;
#pragma unroll
    for (int e = 0; e < 16; e += 4) {
      float4 f = *(const float4*)(W1 + (size_t)(kt0 + row) * 128 + nt0 + c0 + e);
      Tl[row][c0 + e] = f.x; Tl[row][c0 + e + 1] = f.y;
      Tl[row][c0 + e + 2] = f.z; Tl[row][c0 + e + 3] = f.w;
    }
    __syncthreads();
    const int nrow = tid >> 2, kc0 = (tid & 3) * 16;
    _Float16* wp = W1t + (size_t)(nt0 + nrow) * 2048 + kt0 + kc0;
#pragma unroll
    for (int e = 0; e < 16; ++e) wp[e] = (_Float16)Tl[kc0 + e][nrow];
  } else {
    int r = (bid - 64) * 256 + tid;
    if (r < 3 * 16384) {
      int m = r >> 14, e = r & 16383;
      int n = e >> 7, k = e & 127;
      const float* W = (m == 0) ? Wq : (m == 1) ? Wk : Wv;
      Wqkvt[r] = (_Float16)W[k * 128 + n];
    }
  }
}

// ---------------------------------------------------------------------------
// Fused GEMM1 + QKV:
//   h = relu((x + posenc) @ W1 + b1)   (16x128 tile, registers->LDS)
//   {Q,K,V} = h @ {Wq,Wk,Wv}           (epilogue, weights from L2)
// BM=16, BK=128, 512 threads (8 waves), grid 512, double-buffered LDS.
// ---------------------------------------------------------------------------
__global__ __launch_bounds__(512) void k_fused(const float* __restrict__ x,
                                               const _Float16* __restrict__ W1t,
                                               const _Float16* __restrict__ Wqkv,
                                               const float* __restrict__ b1,
                                               _Float16* __restrict__ Qg,
                                               _Float16* __restrict__ Kg,
                                               _Float16* __restrict__ Vg) {
  __shared__ __align__(16) char smem[78336];   // 2 x (Bl 34816 + Al 4352)
  const int tid = threadIdx.x;
  const int lane = tid & 63, wv = tid >> 6;
  const int i0 = blockIdx.x * 16;
  const int arow = tid >> 5, akc = (tid & 31) * 4;   // A stage: 1 float4/thread
  const int brow = tid >> 2, bk = (tid & 3) * 32;    // B stage: 4 half8/thread
  const float sf = (float)((i0 + arow) & 2047);
  const int fr = lane & 15, kg8 = (lane >> 4) * 8;
  const float* xrow = x + (size_t)(i0 + arow) * 2048;
  const _Float16* wrow = W1t + (size_t)brow * 2048;

  auto Albase = [&](int buf) { return (_Float16*)(smem + buf * 39168 + 34816); };
  auto Blbase = [&](int buf) { return (_Float16*)(smem + buf * 39168); };

  // stage helpers ------------------------------------------------------------
  float4 xa;
  half8 wb0, wb1, wb2, wb3;
  auto issue_loads = [&](int kt) {
    xa  = *(const float4*)(xrow + kt + akc);
    wb0 = *(const half8*)(wrow + kt + bk);
    wb1 = *(const half8*)(wrow + kt + bk + 8);
    wb2 = *(const half8*)(wrow + kt + bk + 16);
    wb3 = *(const half8*)(wrow + kt + bk + 24);
  };
  auto write_stage = [&](int buf, int kt) {
    // posenc for k = kt+akc+e ; pairs share k>>1
    const int kb = kt + akc;
    float c0 = exp2f((float)(kb >> 1) * -LOG2_10K_64) * INV2PI;
    float c1 = exp2f((float)((kb >> 1) + 1) * -LOG2_10K_64) * INV2PI;
    float r0 = __builtin_fmaf(sf, c0, -rintf(sf * c0));
    float r1 = __builtin_fmaf(sf, c1, -rintf(sf * c1));
    half4 av;
    av[0] = (_Float16)(xa.x + __builtin_amdgcn_sinf(r0));
    av[1] = (_Float16)(xa.y + __builtin_amdgcn_cosf(r0));
    av[2] = (_Float16)(xa.z + __builtin_amdgcn_sinf(r1));
    av[3] = (_Float16)(xa.w + __builtin_amdgcn_cosf(r1));
    *(half4*)(Albase(buf) + arow * 136 + akc) = av;
    _Float16* bl = Blbase(buf) + brow * 136 + bk;
    *(half8*)(bl)      = wb0;
    *(half8*)(bl + 8)  = wb1;
    *(half8*)(bl + 16) = wb2;
    *(half8*)(bl + 24) = wb3;
  };

  // prologue -----------------------------------------------------------------
  issue_loads(0);
  write_stage(0, 0);
  __syncthreads();

  f32x4 acc = {};
  for (int it = 0; it < 16; ++it) {
    const int cur = it & 1;
    const bool pf = (it < 15);
    if (pf) issue_loads((it + 1) * 128);
    const _Float16* Al = Albase(cur);
    const _Float16* Bl = Blbase(cur) + (wv * 16 + fr) * 136;
#pragma unroll
    for (int kk = 0; kk < 4; ++kk) {
      half8 a = *(const half8*)(Al + fr * 136 + kk * 32 + kg8);
      half8 b = *(const half8*)(Bl + kk * 32 + kg8);
      acc = MFMAH(a, b, acc);
    }
    if (pf) write_stage(cur ^ 1, (it + 1) * 128);
    __syncthreads();
  }

  // epilogue: h -> LDS, then Q/K/V projections -------------------------------
  _Float16* Hs = Albase(0);            // [16][136]
  _Float16* Ws = Blbase(0);            // [128][136]
  {
    const int col = wv * 16 + fr;
    const float bv = b1[col];
#pragma unroll
    for (int r = 0; r < 4; ++r) {
      float v = acc[r] + bv;
      v = v > 0.f ? v : 0.f;
      Hs[((lane >> 4) * 4 + r) * 136 + col] = (_Float16)v;
    }
  }
  __syncthreads();
#pragma unroll 1
  for (int m = 0; m < 3; ++m) {
    const _Float16* Wt = Wqkv + m * 16384 + (size_t)brow * 128;
    _Float16* wl = Ws + brow * 136 + bk;
    *(half8*)(wl)      = *(const half8*)(Wt + bk);
    *(half8*)(wl + 8)  = *(const half8*)(Wt + bk + 8);
    *(half8*)(wl + 16) = *(const half8*)(Wt + bk + 16);
    *(half8*)(wl + 24) = *(const half8*)(Wt + bk + 24);
    __syncthreads();
    f32x4 a2 = {};
#pragma unroll
    for (int kk = 0; kk < 4; ++kk) {
      half8 a = *(const half8*)(Hs + fr * 136 + kk * 32 + kg8);
      half8 b = *(const half8*)(Ws + (wv * 16 + fr) * 136 + kk * 32 + kg8);
      a2 = MFMAH(a, b, a2);
    }
    _Float16* dst = (m == 0) ? Qg : (m == 1) ? Kg : Vg;
#pragma unroll
    for (int r = 0; r < 4; ++r)
      dst[(size_t)(i0 + (lane >> 4) * 4 + r) * 128 + wv * 16 + fr] = (_Float16)a2[r];
    __syncthreads();
  }
}

// ---------------------------------------------------------------------------
// Attention via MFMA. Block = 16 q-rows of one batch; 4 waves; grid 512.
// K-window: lr in [0,80) <-> j = i0-32+lr (zero rows outside sequence ->
// score 0, INCLUDED in softmax, matching reference zero-padding).
// Band mask: q-row r keeps cols lr in [r, r+64] (65 entries).
// ---------------------------------------------------------------------------
__global__ __launch_bounds__(256) void k_attn(const _Float16* __restrict__ Qg,
                                              const _Float16* __restrict__ Kg,
                                              const _Float16* __restrict__ Vg,
                                              const float* __restrict__ Wo,
                                              const float* __restrict__ bo,
                                              float* __restrict__ outp,
                                              float* __restrict__ attwg) {
  __shared__ _Float16 Qs[16][136];
  __shared__ _Float16 Ks[80][136];
  __shared__ _Float16 Vs[96][136];
  __shared__ _Float16 Ps[16][104];
  __shared__ float sc[16][84];
  __shared__ float aw[16 * 65];
  __shared__ float wol[128][2];
  __shared__ float proj[4][16][2];
  const int tid = threadIdx.x;
  const int lane = tid & 63, wv = tid >> 6;
  const int b = blockIdx.x >> 7;
  const int i0 = (blockIdx.x & 127) << 4;
  const int rowbase = b * 2048 + i0;
  const float invscale = 0.08838834764831845f;  // 1/sqrt(128)

  // ---- stage Q (16 rows), K (80 rows), V (96 rows: 80 real + 16 zero) ----
  {
    const int row = tid >> 4, d8 = (tid & 15) * 8;
    *(half8*)&Qs[row][d8] = *(const half8*)(Qg + (size_t)(rowbase + row) * 128 + d8);
  }
#pragma unroll
  for (int it = 0; it < 5; ++it) {
    const int idx = it * 256 + tid;
    const int lr = idx >> 4, d8 = (idx & 15) * 8;
    const int j = i0 - 32 + lr;
    half8 kv = {0, 0, 0, 0, 0, 0, 0, 0};
    if (j >= 0 && j < 2048)
      kv = *(const half8*)(Kg + (size_t)(b * 2048 + j) * 128 + d8);
    *(half8*)&Ks[lr][d8] = kv;
  }
#pragma unroll
  for (int it = 0; it < 6; ++it) {
    const int idx = it * 256 + tid;
    const int lr = idx >> 4, d8 = (idx & 15) * 8;
    const int j = i0 - 32 + lr;
    half8 vv = {0, 0, 0, 0, 0, 0, 0, 0};
    if (lr < 80 && j >= 0 && j < 2048)
      vv = *(const half8*)(Vg + (size_t)(b * 2048 + j) * 128 + d8);
    *(half8*)&Vs[lr][d8] = vv;
  }
  wol[tid >> 1][tid & 1] = Wo[tid];
  __syncthreads();

  const int fr = lane & 15, kg8 = (lane >> 4) * 8;
  // ---- QK^T: C[16 q][80 k] = 5 col-tiles; wave wv -> ct=wv, wave0 also ct=4
  {
    const int nct = (wv == 0) ? 2 : 1;
    for (int p = 0; p < nct; ++p) {
      const int ct = (p == 0) ? wv : 4;
      f32x4 acc = {};
#pragma unroll
      for (int kk = 0; kk < 4; ++kk) {
        half8 a  = *(const half8*)&Qs[fr][kk * 32 + kg8];
        half8 bb = *(const half8*)&Ks[ct * 16 + fr][kk * 32 + kg8];
        acc = MFMAH(a, bb, acc);
      }
#pragma unroll
      for (int r = 0; r < 4; ++r)
        sc[(lane >> 4) * 4 + r][ct * 16 + fr] = acc[r] * invscale;
    }
  }
  __syncthreads();

  // ---- banded softmax; wave wv owns q-rows 4wv..4wv+3 ----
#pragma unroll 1
  for (int rr = 0; rr < 4; ++rr) {
    const int r = wv * 4 + rr;
    const int c0 = lane;
    const bool ib0 = (c0 >= r);               // c0 <= 63 <= r+64 always
    const bool ib1 = (lane <= r);             // col 64+lane <= r+64
    float a0 = ib0 ? sc[r][c0] : -1e30f;
    float a1 = ib1 ? sc[r][64 + lane] : -1e30f;
    float mx = fmaxf(a0, a1);
#pragma unroll
    for (int o = 1; o < 64; o <<= 1) mx = fmaxf(mx, __shfl_xor(mx, o));
    float e0 = ib0 ? __expf(a0 - mx) : 0.f;
    float e1 = ib1 ? __expf(a1 - mx) : 0.f;
    float sm = e0 + e1;
#pragma unroll
    for (int o = 1; o < 64; o <<= 1) sm += __shfl_xor(sm, o);
    const float inv = 1.0f / sm;
    const float w0 = e0 * inv, w1 = e1 * inv;
    if (ib0) aw[r * 65 + (r + 64 - c0)] = w0;   // t = r+64-c in [1..64]
    if (ib1) aw[r * 65 + (r - lane)] = w1;      // t = r-lane in [0..r]
    Ps[r][c0] = (_Float16)w0;
    if (lane < 32) Ps[r][64 + lane] = (_Float16)((lane < 16) ? w1 : 0.f);
  }
  __syncthreads();

  // ---- attw copy-out (contiguous 1040 floats per block) ----
  for (int i = tid; i < 1040; i += 256)
    attwg[(size_t)rowbase * 65 + i] = aw[i];

  // ---- PV: C2[16 q][128 d] = P(16x96) @ V(96x128); wave wv -> d-tiles 2wv,2wv+1
  f32x4 c2[2] = {};
#pragma unroll
  for (int kk = 0; kk < 3; ++kk) {
    half8 a = *(const half8*)&Ps[fr][kk * 32 + kg8];
#pragma unroll
    for (int dt2 = 0; dt2 < 2; ++dt2) {
      const int d = (2 * wv + dt2) * 16 + fr;
      half8 bb;
#pragma unroll
      for (int e = 0; e < 8; ++e) bb[e] = Vs[kk * 32 + kg8 + e][d];
      c2[dt2] = MFMAH(a, bb, c2[dt2]);
    }
  }
  // ---- projection: out[q][o] = invscale * sum_d C2[q][d]*Wo[d][o] + bo[o]
#pragma unroll
  for (int r = 0; r < 4; ++r) {
    float p0 = 0.f, p1 = 0.f;
#pragma unroll
    for (int dt2 = 0; dt2 < 2; ++dt2) {
      const int d = (2 * wv + dt2) * 16 + fr;
      p0 += c2[dt2][r] * wol[d][0];
      p1 += c2[dt2][r] * wol[d][1];
    }
    p0 += __shfl_xor(p0, 1); p0 += __shfl_xor(p0, 2);
    p0 += __shfl_xor(p0, 4); p0 += __shfl_xor(p0, 8);
    p1 += __shfl_xor(p1, 1); p1 += __shfl_xor(p1, 2);
    p1 += __shfl_xor(p1, 4); p1 += __shfl_xor(p1, 8);
    if (fr == 0) {
      const int q = (lane >> 4) * 4 + r;
      proj[wv][q][0] = p0;
      proj[wv][q][1] = p1;
    }
  }
  __syncthreads();
  if (tid < 16) {
    float s0 = proj[0][tid][0] + proj[1][tid][0] + proj[2][tid][0] + proj[3][tid][0];
    float s1 = proj[0][tid][1] + proj[1][tid][1] + proj[2][tid][1] + proj[3][tid][1];
    outp[((size_t)rowbase + tid) * 2 + 0] = s0 * invscale + bo[0];
    outp[((size_t)rowbase + tid) * 2 + 1] = s1 * invscale + bo[1];
  }
}

extern "C" void kernel_launch(void* const* d_in, const int* in_sizes, int n_in,
                              void* d_out, int out_size, void* d_ws, size_t ws_size,
                              hipStream_t stream) {
  const float* x  = (const float*)d_in[0];
  const float* W1 = (const float*)d_in[1];
  const float* b1 = (const float*)d_in[2];
  const float* Wq = (const float*)d_in[3];
  const float* Wk = (const float*)d_in[4];
  const float* Wv = (const float*)d_in[5];
  const float* Wo = (const float*)d_in[6];
  const float* bo = (const float*)d_in[7];
  float* out  = (float*)d_out;            // (4,2048,2)
  float* attw = out + 16384;              // (4,2048,65)

  _Float16* W1t  = (_Float16*)d_ws;       // 128x2048
  _Float16* Wqkv = W1t + 262144;          // 3 x 128x128
  _Float16* Qg   = Wqkv + 49152;          // 8192x128
  _Float16* Kg   = Qg + 1048576;
  _Float16* Vg   = Kg + 1048576;

  k_prep<<<256, 256, 0, stream>>>(W1, Wq, Wk, Wv, W1t, Wqkv);
  k_fused<<<512, 512, 0, stream>>>(x, W1t, Wqkv, b1, Qg, Kg, Vg);
  k_attn<<<512, 256, 0, stream>>>(Qg, Kg, Vg, Wo, bo, out, attw);
}

// Round 5
// 58.056 us; speedup vs baseline: 1.1208x; 1.1208x over previous
//
#include <hip/hip_runtime.h>
#include <hip/hip_bf16.h>

typedef __attribute__((ext_vector_type(8))) _Float16 half8;
typedef __attribute__((ext_vector_type(4))) _Float16 half4;
typedef __attribute__((ext_vector_type(4))) float f32x4;

#define MFMAH(a,b,c) __builtin_amdgcn_mfma_f32_16x16x32_f16(a,b,c,0,0,0)

#define LOG2_10K_64 0.2076205059304595f
#define INV2PI 0.15915494309189535f

// ---------------------------------------------------------------------------
// Prep: W1 (2048x128 f32) -> W1t[n][k] f16 (coalesced LDS-tile transpose);
// Wq/Wk/Wv (128x128) -> transposed f16 concatenated.
// ---------------------------------------------------------------------------
__global__ __launch_bounds__(256) void k_prep(const float* __restrict__ W1,
                                              const float* __restrict__ Wq,
                                              const float* __restrict__ Wk,
                                              const float* __restrict__ Wv,
                                              _Float16* __restrict__ W1t,
                                              _Float16* __restrict__ Wqkvt) {
  const int bid = blockIdx.x, tid = threadIdx.x;
  if (bid < 64) {
    __shared__ float Tl[64][65];
    const int kt0 = (bid >> 1) * 64, nt0 = (bid & 1) * 64;
    const int row = tid >> 2, c0 = (tid & 3) * 16;
#pragma unroll
    for (int e = 0; e < 16; e += 4) {
      float4 f = *(const float4*)(W1 + (size_t)(kt0 + row) * 128 + nt0 + c0 + e);
      Tl[row][c0 + e] = f.x; Tl[row][c0 + e + 1] = f.y;
      Tl[row][c0 + e + 2] = f.z; Tl[row][c0 + e + 3] = f.w;
    }
    __syncthreads();
    const int nrow = tid >> 2, kc0 = (tid & 3) * 16;
    _Float16* wp = W1t + (size_t)(nt0 + nrow) * 2048 + kt0 + kc0;
#pragma unroll
    for (int e = 0; e < 16; ++e) wp[e] = (_Float16)Tl[kc0 + e][nrow];
  } else {
    int r = (bid - 64) * 256 + tid;
    if (r < 3 * 16384) {
      int m = r >> 14, e = r & 16383;
      int n = e >> 7, k = e & 127;
      const float* W = (m == 0) ? Wq : (m == 1) ? Wk : Wv;
      Wqkvt[r] = (_Float16)W[k * 128 + n];
    }
  }
}

// ---------------------------------------------------------------------------
// Fused GEMM1 + QKV. h = relu((x+posenc)@W1+b1); {Q,K,V} = h@{Wq,Wk,Wv}.
// BM=16, BK=128, 512 threads (8 waves, wave wv owns cols 16wv..16wv+15).
// A (x+posenc) double-buffered in tiny LDS; B fragments DIRECT from global
// (W1t n-major, contiguous in k) -> no B staging, no vmcnt-drain before
// barrier, 8.7 KB LDS. Grid 512 (2 blocks/CU).
// ---------------------------------------------------------------------------
__global__ __launch_bounds__(512) void k_fused(const float* __restrict__ x,
                                               const _Float16* __restrict__ W1t,
                                               const _Float16* __restrict__ Wqkv,
                                               const float* __restrict__ b1,
                                               _Float16* __restrict__ Qg,
                                               _Float16* __restrict__ Kg,
                                               _Float16* __restrict__ Vg) {
  __shared__ _Float16 As[2][16][136];
  const int tid = threadIdx.x;
  const int lane = tid & 63, wv = tid >> 6;
  const int fr = lane & 15, kg8 = (lane >> 4) * 8;
  const int i0 = blockIdx.x * 16;
  const int arow = tid >> 5, akc = (tid & 31) * 4;
  const float sf = (float)((i0 + arow) & 2047);
  const float* xrow = x + (size_t)(i0 + arow) * 2048 + akc;
  const _Float16* wrow = W1t + (size_t)(wv * 16 + fr) * 2048 + kg8;

  auto loadB = [&](int s, half8* b) {
    const _Float16* p = wrow + s * 128;
#pragma unroll
    for (int kk = 0; kk < 4; ++kk) b[kk] = *(const half8*)(p + kk * 32);
  };
  auto stageA = [&](int buf, int s, float4 xa) {
    const int kb = s * 128 + akc;
    float c0 = exp2f((float)(kb >> 1) * -LOG2_10K_64) * INV2PI;
    float c1 = exp2f((float)((kb >> 1) + 1) * -LOG2_10K_64) * INV2PI;
    float r0 = __builtin_fmaf(sf, c0, -rintf(sf * c0));
    float r1 = __builtin_fmaf(sf, c1, -rintf(sf * c1));
    half4 av;
    av[0] = (_Float16)(xa.x + __builtin_amdgcn_sinf(r0));
    av[1] = (_Float16)(xa.y + __builtin_amdgcn_cosf(r0));
    av[2] = (_Float16)(xa.z + __builtin_amdgcn_sinf(r1));
    av[3] = (_Float16)(xa.w + __builtin_amdgcn_cosf(r1));
    *(half4*)&As[buf][arow][akc] = av;
  };

  // prologue: x(0),x(1) in flight; B(0) in regs; stage A(0)
  float4 xaA = *(const float4*)(xrow);
  float4 xaB = *(const float4*)(xrow + 128);
  half8 bcur[4], bnxt[4];
  loadB(0, bcur);
  stageA(0, 0, xaA);
  __syncthreads();

  f32x4 acc = {};
  // steady state: 7 guard-free {even,odd} pairs (steps 0..13)
#pragma unroll 1
  for (int i = 0; i < 7; ++i) {
    const int s = 2 * i;
    // even step s: MFMA buf0 with bcur; prefetch x(s+2), B(s+1); stage s+1
    xaA = *(const float4*)(xrow + (s + 2) * 128);
    loadB(s + 1, bnxt);
#pragma unroll
    for (int kk = 0; kk < 4; ++kk) {
      half8 a = *(const half8*)&As[0][fr][kk * 32 + kg8];
      acc = MFMAH(a, bcur[kk], acc);
    }
    stageA(1, s + 1, xaB);
    __syncthreads();
    // odd step s+1: MFMA buf1 with bnxt; prefetch x(s+3), B(s+2); stage s+2
    xaB = *(const float4*)(xrow + (s + 3) * 128);
    loadB(s + 2, bcur);
#pragma unroll
    for (int kk = 0; kk < 4; ++kk) {
      half8 a = *(const half8*)&As[1][fr][kk * 32 + kg8];
      acc = MFMAH(a, bnxt[kk], acc);
    }
    stageA(0, s + 2, xaA);
    __syncthreads();
  }
  // tail: step 14 (stage 15), step 15 (no stage)
  loadB(15, bnxt);
#pragma unroll
  for (int kk = 0; kk < 4; ++kk) {
    half8 a = *(const half8*)&As[0][fr][kk * 32 + kg8];
    acc = MFMAH(a, bcur[kk], acc);
  }
  stageA(1, 15, xaB);
  __syncthreads();
#pragma unroll
  for (int kk = 0; kk < 4; ++kk) {
    half8 a = *(const half8*)&As[1][fr][kk * 32 + kg8];
    acc = MFMAH(a, bnxt[kk], acc);
  }
  __syncthreads();   // all reads of As done before Hs overlay

  // epilogue: h -> LDS (relu+bias), then Q/K/V with B direct from Wqkv
  _Float16 (*Hs)[136] = As[0];
  {
    const int col = wv * 16 + fr;
    const float bv = b1[col];
#pragma unroll
    for (int r = 0; r < 4; ++r) {
      float v = acc[r] + bv;
      v = v > 0.f ? v : 0.f;
      Hs[(lane >> 4) * 4 + r][col] = (_Float16)v;
    }
  }
  __syncthreads();
  const _Float16* wqrow = Wqkv + (size_t)(wv * 16 + fr) * 128 + kg8;
#pragma unroll 1
  for (int m = 0; m < 3; ++m) {
    f32x4 a2 = {};
#pragma unroll
    for (int kk = 0; kk < 4; ++kk) {
      half8 a = *(const half8*)&Hs[fr][kk * 32 + kg8];
      half8 b = *(const half8*)(wqrow + m * 16384 + kk * 32);
      a2 = MFMAH(a, b, a2);
    }
    _Float16* dst = (m == 0) ? Qg : (m == 1) ? Kg : Vg;
#pragma unroll
    for (int r = 0; r < 4; ++r)
      dst[(size_t)(i0 + (lane >> 4) * 4 + r) * 128 + wv * 16 + fr] = (_Float16)a2[r];
  }
}

// ---------------------------------------------------------------------------
// Attention via MFMA. Block = 16 q-rows of one batch; 4 waves; grid 512.
// K-window: lr in [0,80) <-> j = i0-32+lr (zero rows outside sequence ->
// score 0, INCLUDED in softmax, matching reference zero-padding).
// Band mask: q-row r keeps cols lr in [r, r+64] (65 entries).
// ---------------------------------------------------------------------------
__global__ __launch_bounds__(256) void k_attn(const _Float16* __restrict__ Qg,
                                              const _Float16* __restrict__ Kg,
                                              const _Float16* __restrict__ Vg,
                                              const float* __restrict__ Wo,
                                              const float* __restrict__ bo,
                                              float* __restrict__ outp,
                                              float* __restrict__ attwg) {
  __shared__ _Float16 Qs[16][136];
  __shared__ _Float16 Ks[80][136];
  __shared__ _Float16 Vs[96][136];
  __shared__ _Float16 Ps[16][104];
  __shared__ float sc[16][84];
  __shared__ float aw[16 * 65];
  __shared__ float wol[128][2];
  __shared__ float proj[4][16][2];
  const int tid = threadIdx.x;
  const int lane = tid & 63, wv = tid >> 6;
  const int b = blockIdx.x >> 7;
  const int i0 = (blockIdx.x & 127) << 4;
  const int rowbase = b * 2048 + i0;
  const float invscale = 0.08838834764831845f;  // 1/sqrt(128)

  // ---- stage Q (16 rows), K (80 rows), V (96 rows: 80 real + 16 zero) ----
  {
    const int row = tid >> 4, d8 = (tid & 15) * 8;
    *(half8*)&Qs[row][d8] = *(const half8*)(Qg + (size_t)(rowbase + row) * 128 + d8);
  }
#pragma unroll
  for (int it = 0; it < 5; ++it) {
    const int idx = it * 256 + tid;
    const int lr = idx >> 4, d8 = (idx & 15) * 8;
    const int j = i0 - 32 + lr;
    half8 kv = {0, 0, 0, 0, 0, 0, 0, 0};
    if (j >= 0 && j < 2048)
      kv = *(const half8*)(Kg + (size_t)(b * 2048 + j) * 128 + d8);
    *(half8*)&Ks[lr][d8] = kv;
  }
#pragma unroll
  for (int it = 0; it < 6; ++it) {
    const int idx = it * 256 + tid;
    const int lr = idx >> 4, d8 = (idx & 15) * 8;
    const int j = i0 - 32 + lr;
    half8 vv = {0, 0, 0, 0, 0, 0, 0, 0};
    if (lr < 80 && j >= 0 && j < 2048)
      vv = *(const half8*)(Vg + (size_t)(b * 2048 + j) * 128 + d8);
    *(half8*)&Vs[lr][d8] = vv;
  }
  wol[tid >> 1][tid & 1] = Wo[tid];
  __syncthreads();

  const int fr = lane & 15, kg8 = (lane >> 4) * 8;
  // ---- QK^T: C[16 q][80 k] = 5 col-tiles; wave wv -> ct=wv, wave0 also ct=4
  {
    const int nct = (wv == 0) ? 2 : 1;
    for (int p = 0; p < nct; ++p) {
      const int ct = (p == 0) ? wv : 4;
      f32x4 acc = {};
#pragma unroll
      for (int kk = 0; kk < 4; ++kk) {
        half8 a  = *(const half8*)&Qs[fr][kk * 32 + kg8];
        half8 bb = *(const half8*)&Ks[ct * 16 + fr][kk * 32 + kg8];
        acc = MFMAH(a, bb, acc);
      }
#pragma unroll
      for (int r = 0; r < 4; ++r)
        sc[(lane >> 4) * 4 + r][ct * 16 + fr] = acc[r] * invscale;
    }
  }
  __syncthreads();

  // ---- banded softmax; wave wv owns q-rows 4wv..4wv+3 ----
#pragma unroll 1
  for (int rr = 0; rr < 4; ++rr) {
    const int r = wv * 4 + rr;
    const int c0 = lane;
    const bool ib0 = (c0 >= r);               // c0 <= 63 <= r+64 always
    const bool ib1 = (lane <= r);             // col 64+lane <= r+64
    float a0 = ib0 ? sc[r][c0] : -1e30f;
    float a1 = ib1 ? sc[r][64 + lane] : -1e30f;
    float mx = fmaxf(a0, a1);
#pragma unroll
    for (int o = 1; o < 64; o <<= 1) mx = fmaxf(mx, __shfl_xor(mx, o));
    float e0 = ib0 ? __expf(a0 - mx) : 0.f;
    float e1 = ib1 ? __expf(a1 - mx) : 0.f;
    float sm = e0 + e1;
#pragma unroll
    for (int o = 1; o < 64; o <<= 1) sm += __shfl_xor(sm, o);
    const float inv = 1.0f / sm;
    const float w0 = e0 * inv, w1 = e1 * inv;
    if (ib0) aw[r * 65 + (r + 64 - c0)] = w0;   // t = r+64-c in [1..64]
    if (ib1) aw[r * 65 + (r - lane)] = w1;      // t = r-lane in [0..r]
    Ps[r][c0] = (_Float16)w0;
    if (lane < 32) Ps[r][64 + lane] = (_Float16)((lane < 16) ? w1 : 0.f);
  }
  __syncthreads();

  // ---- attw copy-out (contiguous 1040 floats per block) ----
  for (int i = tid; i < 1040; i += 256)
    attwg[(size_t)rowbase * 65 + i] = aw[i];

  // ---- PV: C2[16 q][128 d] = P(16x96) @ V(96x128); wave wv -> d-tiles 2wv,2wv+1
  f32x4 c2[2] = {};
#pragma unroll
  for (int kk = 0; kk < 3; ++kk) {
    half8 a = *(const half8*)&Ps[fr][kk * 32 + kg8];
#pragma unroll
    for (int dt2 = 0; dt2 < 2; ++dt2) {
      const int d = (2 * wv + dt2) * 16 + fr;
      half8 bb;
#pragma unroll
      for (int e = 0; e < 8; ++e) bb[e] = Vs[kk * 32 + kg8 + e][d];
      c2[dt2] = MFMAH(a, bb, c2[dt2]);
    }
  }
  // ---- projection: out[q][o] = invscale * sum_d C2[q][d]*Wo[d][o] + bo[o]
#pragma unroll
  for (int r = 0; r < 4; ++r) {
    float p0 = 0.f, p1 = 0.f;
#pragma unroll
    for (int dt2 = 0; dt2 < 2; ++dt2) {
      const int d = (2 * wv + dt2) * 16 + fr;
      p0 += c2[dt2][r] * wol[d][0];
      p1 += c2[dt2][r] * wol[d][1];
    }
    p0 += __shfl_xor(p0, 1); p0 += __shfl_xor(p0, 2);
    p0 += __shfl_xor(p0, 4); p0 += __shfl_xor(p0, 8);
    p1 += __shfl_xor(p1, 1); p1 += __shfl_xor(p1, 2);
    p1 += __shfl_xor(p1, 4); p1 += __shfl_xor(p1, 8);
    if (fr == 0) {
      const int q = (lane >> 4) * 4 + r;
      proj[wv][q][0] = p0;
      proj[wv][q][1] = p1;
    }
  }
  __syncthreads();
  if (tid < 16) {
    float s0 = proj[0][tid][0] + proj[1][tid][0] + proj[2][tid][0] + proj[3][tid][0];
    float s1 = proj[0][tid][1] + proj[1][tid][1] + proj[2][tid][1] + proj[3][tid][1];
    outp[((size_t)rowbase + tid) * 2 + 0] = s0 * invscale + bo[0];
    outp[((size_t)rowbase + tid) * 2 + 1] = s1 * invscale + bo[1];
  }
}

extern "C" void kernel_launch(void* const* d_in, const int* in_sizes, int n_in,
                              void* d_out, int out_size, void* d_ws, size_t ws_size,
                              hipStream_t stream) {
  const float* x  = (const float*)d_in[0];
  const float* W1 = (const float*)d_in[1];
  const float* b1 = (const float*)d_in[2];
  const float* Wq = (const float*)d_in[3];
  const float* Wk = (const float*)d_in[4];
  const float* Wv = (const float*)d_in[5];
  const float* Wo = (const float*)d_in[6];
  const float* bo = (const float*)d_in[7];
  float* out  = (float*)d_out;            // (4,2048,2)
  float* attw = out + 16384;              // (4,2048,65)

  _Float16* W1t  = (_Float16*)d_ws;       // 128x2048
  _Float16* Wqkv = W1t + 262144;          // 3 x 128x128
  _Float16* Qg   = Wqkv + 49152;          // 8192x128
  _Float16* Kg   = Qg + 1048576;
  _Float16* Vg   = Kg + 1048576;

  k_prep<<<256, 256, 0, stream>>>(W1, Wq, Wk, Wv, W1t, Wqkv);
  k_fused<<<512, 512, 0, stream>>>(x, W1t, Wqkv, b1, Qg, Kg, Vg);
  k_attn<<<512, 256, 0, stream>>>(Qg, Kg, Vg, Wo, bo, out, attw);
}